// Round 1
// baseline (859.633 us; speedup 1.0000x reference)
//
#include <hip/hip_runtime.h>
#include <math.h>

// Problem constants (fixed by setup_inputs)
#define BATCH 32
#define SEQ   4096
#define DIN   1024
#define DOUT  256
#define NSENT 64

// Kernel 1: segment-sum of enc_output over S.
// One block per (b, n) segment row. 256 threads, each owns 4 consecutive
// columns (float4). Reads rows [start, end) of enc[b], accumulates, writes
// seg[row, :] (row = b*64+n) to workspace.
__global__ __launch_bounds__(256) void seg_sum_kernel(
    const float* __restrict__ enc,
    const int* __restrict__ cls_pos,
    const int* __restrict__ last_sep,
    float* __restrict__ seg) {
  const int row = blockIdx.x;          // b*NSENT + n
  const int bb  = row >> 6;
  const int n   = row & 63;

  const int start = cls_pos[bb * NSENT + n];
  int end;
  if (n < NSENT - 1) {
    end = cls_pos[bb * NSENT + n + 1];
  } else {
    end = last_sep[bb] + 1;
    if (end <= start) end = SEQ;       // torch semantics for last segment
  }

  const int t = threadIdx.x;
  const float* base = enc + (size_t)bb * SEQ * DIN + t * 4;

  float4 acc = make_float4(0.f, 0.f, 0.f, 0.f);
  #pragma unroll 4
  for (int s = start; s < end; ++s) {
    const float4 v = *(const float4*)(base + (size_t)s * DIN);
    acc.x += v.x; acc.y += v.y; acc.z += v.z; acc.w += v.w;
  }
  *(float4*)(seg + (size_t)row * DIN + t * 4) = acc;
}

// Kernel 2: out[row, :] = log_softmax(seg[row, :] @ W + len(row) * b)
// Each block handles 8 consecutive rows; 256 threads, thread t owns
// output column t for all 8 rows. seg values have block-uniform addresses
// (scalar-load friendly); W[d, t] loads are coalesced (one 1 KiB row / d).
__global__ __launch_bounds__(256) void gemm_lsm_kernel(
    const float* __restrict__ seg,
    const float* __restrict__ W,
    const float* __restrict__ bias,
    const int* __restrict__ cls_pos,
    const int* __restrict__ last_sep,
    float* __restrict__ out) {
  const int t    = threadIdx.x;
  const int row0 = blockIdx.x * 8;

  float acc[8];
  #pragma unroll
  for (int r = 0; r < 8; ++r) acc[r] = 0.f;

  const float* s0 = seg + (size_t)row0 * DIN;

  for (int d = 0; d < DIN; d += 4) {
    const float w0 = W[(d + 0) * DOUT + t];
    const float w1 = W[(d + 1) * DOUT + t];
    const float w2 = W[(d + 2) * DOUT + t];
    const float w3 = W[(d + 3) * DOUT + t];
    #pragma unroll
    for (int r = 0; r < 8; ++r) {
      const float* sr = s0 + r * DIN + d;   // block-uniform address
      acc[r] = fmaf(sr[0], w0, acc[r]);
      acc[r] = fmaf(sr[1], w1, acc[r]);
      acc[r] = fmaf(sr[2], w2, acc[r]);
      acc[r] = fmaf(sr[3], w3, acc[r]);
    }
  }

  // bias scaled by segment length
  const float bt = bias[t];
  __shared__ float red[8][DOUT];
  __shared__ float m_s[8], l_s[8];

  #pragma unroll
  for (int r = 0; r < 8; ++r) {
    const int row = row0 + r;
    const int bb  = row >> 6;
    const int n   = row & 63;
    const int start = cls_pos[bb * NSENT + n];
    int end;
    if (n < NSENT - 1) {
      end = cls_pos[bb * NSENT + n + 1];
    } else {
      end = last_sep[bb] + 1;
      if (end <= start) end = SEQ;
    }
    int len = end - start;
    if (len < 0) len = 0;
    acc[r] += (float)len * bt;
    red[r][t] = acc[r];
  }
  __syncthreads();

  // per-row max + log-sum-exp: wave w reduces rows 2w and 2w+1
  const int wave = t >> 6;
  const int lane = t & 63;
  for (int k = 0; k < 2; ++k) {
    const int r = wave * 2 + k;
    const float v0 = red[r][lane];
    const float v1 = red[r][lane + 64];
    const float v2 = red[r][lane + 128];
    const float v3 = red[r][lane + 192];
    float m = fmaxf(fmaxf(v0, v1), fmaxf(v2, v3));
    #pragma unroll
    for (int off = 32; off > 0; off >>= 1)
      m = fmaxf(m, __shfl_down(m, off));
    m = __shfl(m, 0);
    float ssum = expf(v0 - m) + expf(v1 - m) + expf(v2 - m) + expf(v3 - m);
    #pragma unroll
    for (int off = 32; off > 0; off >>= 1)
      ssum += __shfl_down(ssum, off);
    if (lane == 0) { m_s[r] = m; l_s[r] = logf(ssum); }
  }
  __syncthreads();

  #pragma unroll
  for (int r = 0; r < 8; ++r)
    out[(size_t)(row0 + r) * DOUT + t] = acc[r] - m_s[r] - l_s[r];
}

extern "C" void kernel_launch(void* const* d_in, const int* in_sizes, int n_in,
                              void* d_out, int out_size, void* d_ws, size_t ws_size,
                              hipStream_t stream) {
  const float* enc      = (const float*)d_in[0];  // [B,S,DIN] fp32
  const float* W        = (const float*)d_in[1];  // [DIN,DOUT] fp32
  const float* bias     = (const float*)d_in[2];  // [DOUT] fp32
  // d_in[3] = max_num_sent (scalar) — compile-time constant here
  const int* cls_pos    = (const int*)d_in[4];    // [B,NSENT] int32
  const int* last_sep   = (const int*)d_in[5];    // [B] int32
  float* out            = (float*)d_out;          // [B,NSENT,DOUT] fp32

  float* seg = (float*)d_ws;                      // [B*NSENT, DIN] = 8 MiB

  seg_sum_kernel<<<BATCH * NSENT, 256, 0, stream>>>(enc, cls_pos, last_sep, seg);
  gemm_lsm_kernel<<<(BATCH * NSENT) / 8, 256, 0, stream>>>(
      seg, W, bias, cls_pos, last_sep, out);
}

// Round 2
// 760.775 us; speedup vs baseline: 1.1299x; 1.1299x over previous
//
#include <hip/hip_runtime.h>
#include <math.h>

// Problem constants (fixed by setup_inputs)
#define BATCH 32
#define SEQ   4096
#define DIN   1024
#define DOUT  256
#define NSENT 64
#define NROWS (BATCH * NSENT)   // 2048 segment rows
#define SPLIT 4                 // sub-blocks per segment (row-interleaved)

__device__ __forceinline__ void seg_bounds(const int* __restrict__ cls_pos,
                                           const int* __restrict__ last_sep,
                                           int row, int& start, int& end) {
  const int bb = row >> 6;
  const int n  = row & 63;
  start = cls_pos[bb * NSENT + n];
  if (n < NSENT - 1) {
    end = cls_pos[bb * NSENT + n + 1];
  } else {
    end = last_sep[bb] + 1;
    if (end <= start) end = SEQ;   // torch semantics for last segment
  }
}

// Kernel 1: partial segment-sums. Block (row*SPLIT + j) sums rows
// start+j, start+j+SPLIT, ... of segment `row`. 256 threads x float4 = 1024
// cols, each row read is 4 KiB fully coalesced. 8192 blocks = 4x chip
// residency -> straggler segments (max ~400 rows) are split 4-way and
// scheduling smooths the tail.
__global__ __launch_bounds__(256) void seg_sum_part(
    const float* __restrict__ enc,
    const int* __restrict__ cls_pos,
    const int* __restrict__ last_sep,
    float* __restrict__ partial) {
  const int blk = blockIdx.x;
  const int row = blk >> 2;
  const int j   = blk & (SPLIT - 1);
  int start, end;
  seg_bounds(cls_pos, last_sep, row, start, end);

  const int t = threadIdx.x;
  const float* base = enc + (size_t)(row >> 6) * SEQ * DIN + t * 4;

  float4 acc = make_float4(0.f, 0.f, 0.f, 0.f);
  #pragma unroll 4
  for (int s = start + j; s < end; s += SPLIT) {
    const float4 v = *(const float4*)(base + (size_t)s * DIN);
    acc.x += v.x; acc.y += v.y; acc.z += v.z; acc.w += v.w;
  }
  *(float4*)(partial + (size_t)blk * DIN + t * 4) = acc;
}

// Kernel 1b: combine the SPLIT partials per segment. Pure L2 traffic
// (32 MiB read, 8 MiB write) -> a few us.
__global__ __launch_bounds__(256) void seg_combine(
    const float* __restrict__ partial,
    float* __restrict__ seg) {
  const int row = blockIdx.x;
  const int t   = threadIdx.x;
  const float* p = partial + (size_t)row * SPLIT * DIN + t * 4;
  float4 a = *(const float4*)(p);
  const float4 b = *(const float4*)(p + DIN);
  const float4 c = *(const float4*)(p + 2 * DIN);
  const float4 d = *(const float4*)(p + 3 * DIN);
  a.x += b.x + c.x + d.x;
  a.y += b.y + c.y + d.y;
  a.z += b.z + c.z + d.z;
  a.w += b.w + c.w + d.w;
  *(float4*)(seg + (size_t)row * DIN + t * 4) = a;
}

// Kernel 2: out[row,:] = log_softmax(seg[row,:] @ W + len(row)*b).
// 4 rows/block -> 512 blocks (2 blocks/CU, 8 waves/CU for latency hiding).
// Thread t owns output column t. seg loads are block-uniform float4
// (scalar-load friendly); W[d,t] loads are coalesced 1 KiB rows.
__global__ __launch_bounds__(256) void gemm_lsm_kernel(
    const float* __restrict__ seg,
    const float* __restrict__ W,
    const float* __restrict__ bias,
    const int* __restrict__ cls_pos,
    const int* __restrict__ last_sep,
    float* __restrict__ out) {
  const int t    = threadIdx.x;
  const int row0 = blockIdx.x * 4;

  float acc[4] = {0.f, 0.f, 0.f, 0.f};
  const float* s0 = seg + (size_t)row0 * DIN;

  for (int d = 0; d < DIN; d += 8) {
    float w[8];
    #pragma unroll
    for (int k = 0; k < 8; ++k) w[k] = W[(d + k) * DOUT + t];
    #pragma unroll
    for (int r = 0; r < 4; ++r) {
      const float* sr = s0 + r * DIN + d;        // block-uniform address
      const float4 sa = *(const float4*)(sr);
      const float4 sb = *(const float4*)(sr + 4);
      acc[r] = fmaf(sa.x, w[0], acc[r]);
      acc[r] = fmaf(sa.y, w[1], acc[r]);
      acc[r] = fmaf(sa.z, w[2], acc[r]);
      acc[r] = fmaf(sa.w, w[3], acc[r]);
      acc[r] = fmaf(sb.x, w[4], acc[r]);
      acc[r] = fmaf(sb.y, w[5], acc[r]);
      acc[r] = fmaf(sb.z, w[6], acc[r]);
      acc[r] = fmaf(sb.w, w[7], acc[r]);
    }
  }

  // bias scaled by segment length
  const float bt = bias[t];
  __shared__ float red[4][DOUT];
  __shared__ float m_s[4], l_s[4];

  #pragma unroll
  for (int r = 0; r < 4; ++r) {
    int start, end;
    seg_bounds(cls_pos, last_sep, row0 + r, start, end);
    int len = end - start;
    if (len < 0) len = 0;
    acc[r] += (float)len * bt;
    red[r][t] = acc[r];
  }
  __syncthreads();

  // per-row max + log-sum-exp: wave w reduces row w
  const int wave = t >> 6;
  const int lane = t & 63;
  {
    const int r = wave;
    const float v0 = red[r][lane];
    const float v1 = red[r][lane + 64];
    const float v2 = red[r][lane + 128];
    const float v3 = red[r][lane + 192];
    float m = fmaxf(fmaxf(v0, v1), fmaxf(v2, v3));
    #pragma unroll
    for (int off = 32; off > 0; off >>= 1)
      m = fmaxf(m, __shfl_down(m, off));
    m = __shfl(m, 0);
    float ssum = expf(v0 - m) + expf(v1 - m) + expf(v2 - m) + expf(v3 - m);
    #pragma unroll
    for (int off = 32; off > 0; off >>= 1)
      ssum += __shfl_down(ssum, off);
    if (lane == 0) { m_s[r] = m; l_s[r] = logf(ssum); }
  }
  __syncthreads();

  #pragma unroll
  for (int r = 0; r < 4; ++r)
    out[(size_t)(row0 + r) * DOUT + t] = acc[r] - m_s[r] - l_s[r];
}

extern "C" void kernel_launch(void* const* d_in, const int* in_sizes, int n_in,
                              void* d_out, int out_size, void* d_ws, size_t ws_size,
                              hipStream_t stream) {
  const float* enc      = (const float*)d_in[0];  // [B,S,DIN] fp32
  const float* W        = (const float*)d_in[1];  // [DIN,DOUT] fp32
  const float* bias     = (const float*)d_in[2];  // [DOUT] fp32
  // d_in[3] = max_num_sent (scalar) — compile-time constant here
  const int* cls_pos    = (const int*)d_in[4];    // [B,NSENT] int32
  const int* last_sep   = (const int*)d_in[5];    // [B] int32
  float* out            = (float*)d_out;          // [B,NSENT,DOUT] fp32

  float* partial = (float*)d_ws;                          // [NROWS*SPLIT, DIN] = 32 MiB
  float* seg     = partial + (size_t)NROWS * SPLIT * DIN; // [NROWS, DIN] = 8 MiB

  seg_sum_part<<<NROWS * SPLIT, 256, 0, stream>>>(enc, cls_pos, last_sep, partial);
  seg_combine<<<NROWS, 256, 0, stream>>>(partial, seg);
  gemm_lsm_kernel<<<NROWS / 4, 256, 0, stream>>>(
      seg, W, bias, cls_pos, last_sep, out);
}